// Round 13
// baseline (367.062 us; speedup 1.0000x reference)
//
#include <hip/hip_runtime.h>

// Problem constants
#define B_   4
#define O_   1000
#define R_   20000
#define NF_  6
#define EDP_ 128   // ED=100 padded to 128
#define KS_  25    // k-split for aggregation
#define CHUNK_ 800 // R_/KS_
#define MPAD_ 1024 // M=1000 padded

// ws layout (in floats):
//   bmp : [2][80000][16]           = 2,560,000 floats
//   Et  : [4][128][20000] bf16     = 10,240,000 bf16 = 5,120,000 float slots
//   RRb : [4][1000][20000] bf16    = 80,000,000 bf16 = 40,000,000 float slots
//   part: [25][4][1024][128] f32   = 13,107,200 floats
//   Wt  : ALIASES head of part region. Written by k_prep, read by k_mlp,
//         then overwritten by k_agg (stream-serial => safe).
// total = 60.8M floats = 243 MB (ws >= 1.28 GB per harness fill)
#define ET_OFF   2560000
#define RRB_OFF  7680000
#define PART_OFF 47680000
#define WT_USHORTS (4 * 2 * 25600)

typedef short bf16x8 __attribute__((ext_vector_type(8)));
typedef float f32x4  __attribute__((ext_vector_type(4)));
typedef unsigned short ushort4v __attribute__((ext_vector_type(4)));
typedef unsigned short ushort8v __attribute__((ext_vector_type(8)));

#define MFMA16 __builtin_amdgcn_mfma_f32_16x16x32_bf16

__device__ __forceinline__ unsigned short f2bf(float x) {
    union { float f; unsigned int u; } v; v.f = x;
    unsigned int r = (v.u + 0x7FFFu + ((v.u >> 16) & 1u)) >> 16;  // RNE
    return (unsigned short)r;
}

__device__ __forceinline__ float bf2f(unsigned short h) {
    union { unsigned int u; float f; } v; v.u = (unsigned int)h << 16;
    return v.f;
}

// ---------------- Kernel 0: weight prep (bf16 hi/lo transposed) -------------
__global__ __launch_bounds__(256) void k_prep(
    const float* __restrict__ rw1, const float* __restrict__ rb1,
    const float* __restrict__ rw2, const float* __restrict__ rb2,
    const float* __restrict__ rw3, const float* __restrict__ rb3,
    const float* __restrict__ rw4, const float* __restrict__ rb4,
    unsigned short* __restrict__ Wt, float* __restrict__ bfp)
{
    const int l = blockIdx.y;
    const float* Ws[4] = {rw1, rw2, rw3, rw4};
    const float* Bs[4] = {rb1, rb2, rb3, rb4};
    const int   Ksz[4] = {13, 150, 150, 150};
    const int   Nsz[4] = {150, 150, 150, 100};
    const float* w = Ws[l];
    const int K = Ksz[l], N = Nsz[l];

    int idx = blockIdx.x * 256 + threadIdx.x;   // 0..25599
    if (idx < 25600) {
        int n = idx / 160, k = idx % 160;
        float v = (k < K && n < N) ? w[k * N + n] : 0.f;
        unsigned short h = f2bf(v);
        unsigned short lo = f2bf(v - bf2f(h));
        Wt[(size_t)l * 51200 + idx]         = h;
        Wt[(size_t)l * 51200 + 25600 + idx] = lo;
    }
    if (blockIdx.x == 0 && threadIdx.x < 160)
        bfp[l * 160 + threadIdx.x] = (threadIdx.x < (unsigned)N) ? Bs[l][threadIdx.x] : 0.f;
}

// ---------------- Kernel 1: marshalling + RR->bf16 spill --------------------
// Round-0 proven read structure (~150us: read-request-rate bound; six
// restructurings R7-R11 all failed to beat it). NEW: each rv (RR value)
// already in-register is also stored as bf16 to RRb[b][n][r], so k_agg
// reads half the cachelines (bf16 vs fp32) and skips its f2bf work.
// Writes ride the store path (fill kernel proves ~105 G-lines/s writes),
// predicted ~free next to the read-bound loop.
__global__ __launch_bounds__(256) void k_marshal(
    const float* __restrict__ obj, const float* __restrict__ S,
    const float* __restrict__ RRm, const float* __restrict__ rinfo,
    float* __restrict__ bmp, unsigned short* __restrict__ RRb)
{
    __shared__ float sobj[500 * NF_];
    const int b = blockIdx.y, z = blockIdx.z;
    const int n0 = z * 500;
    for (int i = threadIdx.x; i < 500 * NF_; i += 256)
        sobj[i] = obj[(size_t)b * O_ * NF_ + (size_t)n0 * NF_ + i];
    __syncthreads();

    const int r = blockIdx.x * 256 + threadIdx.x;
    if (r >= R_) return;

    const size_t base = (size_t)b * O_ * R_ + (size_t)n0 * R_ + r;
    const float* Sp = S + base;
    const float* Rp = RRm + base;
    unsigned short* Rb = RRb + base;   // same [b][n][r] indexing, bf16

    float ss[NF_] = {0.f, 0.f, 0.f, 0.f, 0.f, 0.f};
    float rs[NF_] = {0.f, 0.f, 0.f, 0.f, 0.f, 0.f};

    #pragma unroll 4
    for (int n = 0; n < 500; ++n) {
        float sv = Sp[(size_t)n * R_];
        float rv = Rp[(size_t)n * R_];
        Rb[(size_t)n * R_] = f2bf(rv);   // spill bf16 copy for k_agg
        #pragma unroll
        for (int f = 0; f < NF_; ++f) {
            float o = sobj[n * NF_ + f];
            ss[f] = fmaf(sv, o, ss[f]);
            rs[f] = fmaf(rv, o, rs[f]);
        }
    }

    float* outp = bmp + ((size_t)z * 80000 + (size_t)b * R_ + r) * 16;
    #pragma unroll
    for (int f = 0; f < NF_; ++f) {
        outp[f]     = ss[f];
        outp[6 + f] = rs[f];
    }
    outp[12] = (z == 0) ? rinfo[(size_t)b * R_ + r] : 0.f;
}

// ---------------- Kernel 2: relational MLP, 2M x 2N wave split (R12 WIN) ----
template<int NT>
__device__ __forceinline__ void layer_mmW(
    const unsigned short (*act)[168],
    const unsigned short* __restrict__ Wh, const unsigned short* __restrict__ Wl,
    int arow0, int koff, int cl, int nb, f32x4 (*acc)[5])
{
    #pragma unroll
    for (int m = 0; m < 2; ++m)
        #pragma unroll
        for (int j = 0; j < NT; ++j) acc[m][j] = (f32x4){0.f, 0.f, 0.f, 0.f};
    #pragma unroll
    for (int ks = 0; ks < 5; ++ks) {
        bf16x8 a0 = *(const bf16x8*)&act[arow0][ks * 32 + koff];
        bf16x8 a1 = *(const bf16x8*)&act[arow0 + 16][ks * 32 + koff];
        #pragma unroll
        for (int j = 0; j < NT; ++j) {
            const size_t wo = (size_t)((nb + j) * 16 + cl) * 160 + ks * 32 + koff;
            bf16x8 wh = *(const bf16x8*)(Wh + wo);
            bf16x8 wl = *(const bf16x8*)(Wl + wo);
            acc[0][j] = MFMA16(a0, wh, acc[0][j], 0, 0, 0);
            acc[0][j] = MFMA16(a0, wl, acc[0][j], 0, 0, 0);
            acc[1][j] = MFMA16(a1, wh, acc[1][j], 0, 0, 0);
            acc[1][j] = MFMA16(a1, wl, acc[1][j], 0, 0, 0);
        }
    }
}

template<int NT>
__device__ __forceinline__ void epiW(
    f32x4 (*acc)[5], const float* __restrict__ bias,
    unsigned short (*out)[168], int m0, int cl, int rg0, int nb)
{
    #pragma unroll
    for (int m = 0; m < 2; ++m) {
        #pragma unroll
        for (int j = 0; j < NT; ++j) {
            int col = (nb + j) * 16 + cl;
            float bv = bias[col];
            #pragma unroll
            for (int rg = 0; rg < 4; ++rg) {
                float v = fmaxf(acc[m][j][rg] + bv, 0.f);
                out[m0 + m * 16 + rg0 + rg][col] = f2bf(v);
            }
        }
    }
}

__global__ __launch_bounds__(256) void k_mlp(
    const float* __restrict__ bmp, unsigned short* __restrict__ Et,
    const unsigned short* __restrict__ Wt, const float* __restrict__ bfp)
{
    __shared__ unsigned short act[64][168];   // single buffer, in-place layers
    __shared__ unsigned short alo[64][32];    // lo part of layer-1 input
    const int t = threadIdx.x;
    const size_t row0 = (size_t)blockIdx.x * 64;

    for (int idx = t; idx < 64 * 32; idx += 256) {
        int rr = idx >> 5, k = idx & 31;
        float v = 0.f;
        if (k < 13)
            v = bmp[(row0 + rr) * 16 + k]
              + bmp[(size_t)80000 * 16 + (row0 + rr) * 16 + k];
        unsigned short h = f2bf(v);
        act[rr][k] = h;
        alo[rr][k] = f2bf(v - bf2f(h));
    }
    __syncthreads();

    const int lane = t & 63, wave = t >> 6;
    const int wm = wave >> 1, wn = wave & 1;
    const int m0    = wm * 32;
    const int arow0 = m0 + (lane & 15);
    const int koff  = (lane >> 4) * 8;
    const int cl    = lane & 15;
    const int rg0   = (lane >> 4) * 4;

    f32x4 acc[2][5];

    // ---- layer 1: K=32, split A and split W (3 MFMA per (m, n-tile))
    {
        const unsigned short* Wh = Wt;
        const unsigned short* Wl = Wt + 25600;
        bf16x8 ah0 = *(const bf16x8*)&act[arow0][koff];
        bf16x8 al0 = *(const bf16x8*)&alo[arow0][koff];
        bf16x8 ah1 = *(const bf16x8*)&act[arow0 + 16][koff];
        bf16x8 al1 = *(const bf16x8*)&alo[arow0 + 16][koff];
        #pragma unroll
        for (int j = 0; j < 5; ++j) {
            const size_t wo = (size_t)((wn * 5 + j) * 16 + cl) * 160 + koff;
            bf16x8 wh = *(const bf16x8*)(Wh + wo);
            bf16x8 wl = *(const bf16x8*)(Wl + wo);
            f32x4 a = (f32x4){0.f, 0.f, 0.f, 0.f};
            a = MFMA16(ah0, wh, a, 0, 0, 0);
            a = MFMA16(ah0, wl, a, 0, 0, 0);
            a = MFMA16(al0, wh, a, 0, 0, 0);
            acc[0][j] = a;
            f32x4 c = (f32x4){0.f, 0.f, 0.f, 0.f};
            c = MFMA16(ah1, wh, c, 0, 0, 0);
            c = MFMA16(ah1, wl, c, 0, 0, 0);
            c = MFMA16(al1, wh, c, 0, 0, 0);
            acc[1][j] = c;
        }
    }
    __syncthreads();
    epiW<5>(acc, bfp + 0 * 160, act, m0, cl, rg0, wn * 5);
    __syncthreads();

    // ---- layers 2, 3 (N=150 -> 10 tiles, 5 per wn)
    layer_mmW<5>(act, Wt + 1 * 51200, Wt + 1 * 51200 + 25600, arow0, koff, cl, wn * 5, acc);
    __syncthreads();
    epiW<5>(acc, bfp + 1 * 160, act, m0, cl, rg0, wn * 5);
    __syncthreads();

    layer_mmW<5>(act, Wt + 2 * 51200, Wt + 2 * 51200 + 25600, arow0, koff, cl, wn * 5, acc);
    __syncthreads();
    epiW<5>(acc, bfp + 2 * 160, act, m0, cl, rg0, wn * 5);
    __syncthreads();

    // ---- layer 4 (N=100 -> 7 tiles: wn=0 takes 4, wn=1 takes 3)
    if (wn == 0)
        layer_mmW<4>(act, Wt + 3 * 51200, Wt + 3 * 51200 + 25600, arow0, koff, cl, 0, acc);
    else
        layer_mmW<3>(act, Wt + 3 * 51200, Wt + 3 * 51200 + 25600, arow0, koff, cl, 4, acc);
    __syncthreads();
    if (wn == 0)
        epiW<4>(acc, bfp + 3 * 160, act, m0, cl, rg0, 0);
    else
        epiW<3>(acc, bfp + 3 * 160, act, m0, cl, rg0, 4);
    __syncthreads();

    // write E transposed bf16: Et[b][j][r], rows j=100..127 zeroed
    for (int idx = t; idx < 64 * 128; idx += 256) {
        int rr = idx & 63, j = idx >> 6;
        size_t gr = row0 + rr;
        int b = (int)(gr / R_);
        int r = (int)(gr - (size_t)b * R_);
        Et[((size_t)(b * EDP_ + j)) * R_ + r] = (j < 100) ? act[rr][j] : (unsigned short)0;
    }
}

// ---------------- Kernel 3: aggregation, M=128, bf16 A from RRb -------------
// per (mt, b, kz): C[128x128] += RRb[128 x 800] @ E[800 x 128]
// grid (8, 4, 25), 256 threads = 4 waves; wave w owns rows w*32..w*32+31
// (two 16-row m-groups), all 128 cols (8 n-tiles).
// A: per-lane 16B bf16 loads from RRb (pre-converted by k_marshal — half the
// cachelines of the old fp32 reads, no f2bf in the loop). B: double-buffered
// LDS [2][128][36], one barrier per k-step of 32, loads issued early.
__global__ __launch_bounds__(256) void k_agg(
    const unsigned short* __restrict__ RRb, const unsigned short* __restrict__ Et,
    float* __restrict__ part)
{
    __shared__ unsigned short sB[2][128][36];   // pad 36: 18-dword row stride
    const int t = threadIdx.x;
    const int mt = blockIdx.x, b = blockIdx.y, kz = blockIdx.z;
    const int lane = t & 63, wave = t >> 6;
    const int k0 = kz * CHUNK_;

    // B-stage: 128 rows x 32 bf16 per k-step = 512 x 16B chunks; 2 per thread
    const int br0 = t >> 2, bc0 = (t & 3) * 8;       // rows 0..63
    const int br1 = br0 + 64;                        // rows 64..127
    const unsigned short* EtB = Et + (size_t)b * EDP_ * R_;

    // A: two per-lane rows (m-groups), clamped (rows >=1000 dup 999; their
    // part rows are padding, never read by k_obj)
    const int cl = lane & 15, koff = (lane >> 4) * 8;
    int n0 = mt * 128 + wave * 32 + cl;
    int n1 = n0 + 16;
    if (n0 > 999) n0 = 999;
    if (n1 > 999) n1 = 999;
    const short* Ap0 = (const short*)(RRb + ((size_t)(b * O_) + n0) * R_ + k0 + koff);
    const short* Ap1 = (const short*)(RRb + ((size_t)(b * O_) + n1) * R_ + k0 + koff);

    f32x4 acc[2][8] = {};
    bf16x8 af0c, af1c;
    bf16x8 af0n = {}, af1n = {};

    // prologue: stage B + load A for iter 0
    {
        ushort8v v0 = *(const ushort8v*)(EtB + (size_t)br0 * R_ + k0 + bc0);
        ushort8v v1 = *(const ushort8v*)(EtB + (size_t)br1 * R_ + k0 + bc0);
        *(ushort8v*)&sB[0][br0][bc0] = v0;
        *(ushort8v*)&sB[0][br1][bc0] = v1;
        af0c = *(const bf16x8*)(Ap0);
        af1c = *(const bf16x8*)(Ap1);
    }
    __syncthreads();

    for (int it = 0; it < CHUNK_ / 32; ++it) {
        const int cur = it & 1, nxt = cur ^ 1;
        const bool more = (it + 1 < CHUNK_ / 32);
        ushort8v v0, v1;
        if (more) {
            // issue next-iter loads EARLY (hide HBM latency under MFMA phase)
            const int kb = k0 + (it + 1) * 32;
            v0 = *(const ushort8v*)(EtB + (size_t)br0 * R_ + kb + bc0);
            v1 = *(const ushort8v*)(EtB + (size_t)br1 * R_ + kb + bc0);
            af0n = *(const bf16x8*)(Ap0 + (it + 1) * 32);
            af1n = *(const bf16x8*)(Ap1 + (it + 1) * 32);
        }
        #pragma unroll
        for (int ni = 0; ni < 8; ++ni) {
            bf16x8 bf = *(const bf16x8*)&sB[cur][ni * 16 + cl][koff];
            acc[0][ni] = MFMA16(af0c, bf, acc[0][ni], 0, 0, 0);
            acc[1][ni] = MFMA16(af1c, bf, acc[1][ni], 0, 0, 0);
        }
        if (more) {
            *(ushort8v*)&sB[nxt][br0][bc0] = v0;
            *(ushort8v*)&sB[nxt][br1][bc0] = v1;
        }
        __syncthreads();
        af0c = af0n; af1c = af1n;
    }

    // store partials: C/D layout col=lane&15, row=(lane>>4)*4+rg
    float* pp = part + ((size_t)(kz * 4 + b) * MPAD_) * 128;
    #pragma unroll
    for (int mg = 0; mg < 2; ++mg) {
        const int rowb = mt * 128 + wave * 32 + mg * 16 + (lane >> 4) * 4;
        #pragma unroll
        for (int ni = 0; ni < 8; ++ni)
            #pragma unroll
            for (int rg = 0; rg < 4; ++rg)
                pp[(size_t)(rowb + rg) * 128 + ni * 16 + cl] = acc[mg][ni][rg];
    }
}

// ---------------- Kernel 4: object MLP (sums agg partials) ------------------
__global__ __launch_bounds__(256) void k_obj(
    const float* __restrict__ obj, const float* __restrict__ part,
    const float* __restrict__ ow1, const float* __restrict__ ob1,
    const float* __restrict__ ow2, const float* __restrict__ ob2,
    float* __restrict__ out)
{
    __shared__ float C[8][112];
    __shared__ float h[8][104];
    const int t = threadIdx.x;
    const int g0 = blockIdx.x * 8;

    for (int idx = t; idx < 8 * NF_; idx += 256) {
        int rr = idx / NF_, f = idx % NF_;
        C[rr][f] = obj[(size_t)(g0 + rr) * NF_ + f];
    }
    for (int idx = t; idx < 8 * 100; idx += 256) {
        int rr = idx / 100, f = idx % 100;
        int g = g0 + rr, b = g / 1000, n = g % 1000;
        float s = 0.f;
        for (int z = 0; z < KS_; ++z)
            s += part[((size_t)(z * 4 + b) * MPAD_ + n) * 128 + f];
        C[rr][6 + f] = s;
    }
    __syncthreads();

    for (int idx = t; idx < 8 * 100; idx += 256) {
        int rr = idx / 100, j = idx % 100;
        float acc = ob1[j];
        for (int k = 0; k < 106; ++k)
            acc = fmaf(C[rr][k], ow1[k * 100 + j], acc);
        h[rr][j] = fmaxf(acc, 0.f);
    }
    __syncthreads();

    if (t < 16) {
        int rr = t >> 1, j = t & 1;
        float acc = ob2[j];
        for (int k = 0; k < 100; ++k)
            acc = fmaf(h[rr][k], ow2[k * 2 + j], acc);
        out[(size_t)(g0 + rr) * 2 + j] = acc;
    }
}

// ---------------- launch ----------------------------------------------------
extern "C" void kernel_launch(void* const* d_in, const int* in_sizes, int n_in,
                              void* d_out, int out_size, void* d_ws, size_t ws_size,
                              hipStream_t stream)
{
    const float* obj   = (const float*)d_in[0];
    const float* S     = (const float*)d_in[1];
    const float* RRm   = (const float*)d_in[2];
    const float* rinfo = (const float*)d_in[3];
    const float* rw1   = (const float*)d_in[4];
    const float* rb1   = (const float*)d_in[5];
    const float* rw2   = (const float*)d_in[6];
    const float* rb2   = (const float*)d_in[7];
    const float* rw3   = (const float*)d_in[8];
    const float* rb3   = (const float*)d_in[9];
    const float* rw4   = (const float*)d_in[10];
    const float* rb4   = (const float*)d_in[11];
    const float* ow1   = (const float*)d_in[12];
    const float* ob1   = (const float*)d_in[13];
    const float* ow2   = (const float*)d_in[14];
    const float* ob2   = (const float*)d_in[15];

    float* ws            = (float*)d_ws;
    float* bmp           = ws;
    unsigned short* Et   = (unsigned short*)(ws + ET_OFF);
    unsigned short* RRb  = (unsigned short*)(ws + RRB_OFF);
    float* part          = ws + PART_OFF;
    unsigned short* Wt   = (unsigned short*)(ws + PART_OFF);  // aliases part head
    float* bfp           = ws + PART_OFF + (WT_USHORTS / 2);
    float* out           = (float*)d_out;

    k_prep<<<dim3(100, 4), 256, 0, stream>>>(rw1, rb1, rw2, rb2, rw3, rb3, rw4, rb4,
                                             Wt, bfp);
    k_marshal<<<dim3(79, 4, 2), 256, 0, stream>>>(obj, S, RRm, rinfo, bmp, RRb);
    k_mlp<<<dim3(1250), 256, 0, stream>>>(bmp, Et, Wt, bfp);
    k_agg<<<dim3(8, 4, KS_), 256, 0, stream>>>(RRb, Et, part);
    k_obj<<<dim3(500), 256, 0, stream>>>(obj, part, ow1, ob1, ow2, ob2, out);
}

// Round 14
// 339.227 us; speedup vs baseline: 1.0821x; 1.0821x over previous
//
#include <hip/hip_runtime.h>

// Problem constants
#define B_   4
#define O_   1000
#define R_   20000
#define NF_  6
#define EDP_ 128   // ED=100 padded to 128
#define KS_  25    // k-split for aggregation
#define CHUNK_ 800 // R_/KS_
#define MPAD_ 1024 // M=1000 padded

// ws layout (in floats)  — R12 layout (RRb spill reverted: R13 showed
// read/write lines cost the same in mixed kernels; spill is net-zero):
//   bmp : [2][80000][16]           = 2,560,000 floats
//   Et  : [4][128][20000] bf16     = 10,240,000 bf16 = 5,120,000 float slots
//   part: [25][4][1024][128] f32   = 13,107,200 floats
//   Wt  : ALIASES head of part region (prep->mlp->overwritten by agg).
#define ET_OFF   2560000
#define PART_OFF 7680000
#define WT_USHORTS (4 * 2 * 25600)

typedef short bf16x8 __attribute__((ext_vector_type(8)));
typedef float f32x4  __attribute__((ext_vector_type(4)));
typedef unsigned short ushort4v __attribute__((ext_vector_type(4)));
typedef unsigned short ushort8v __attribute__((ext_vector_type(8)));

#define MFMA16 __builtin_amdgcn_mfma_f32_16x16x32_bf16

__device__ __forceinline__ unsigned short f2bf(float x) {
    union { float f; unsigned int u; } v; v.f = x;
    unsigned int r = (v.u + 0x7FFFu + ((v.u >> 16) & 1u)) >> 16;  // RNE
    return (unsigned short)r;
}

__device__ __forceinline__ float bf2f(unsigned short h) {
    union { unsigned int u; float f; } v; v.u = (unsigned int)h << 16;
    return v.f;
}

// ---------------- Kernel 0: weight prep (bf16 hi/lo transposed) -------------
__global__ __launch_bounds__(256) void k_prep(
    const float* __restrict__ rw1, const float* __restrict__ rb1,
    const float* __restrict__ rw2, const float* __restrict__ rb2,
    const float* __restrict__ rw3, const float* __restrict__ rb3,
    const float* __restrict__ rw4, const float* __restrict__ rb4,
    unsigned short* __restrict__ Wt, float* __restrict__ bfp)
{
    const int l = blockIdx.y;
    const float* Ws[4] = {rw1, rw2, rw3, rw4};
    const float* Bs[4] = {rb1, rb2, rb3, rb4};
    const int   Ksz[4] = {13, 150, 150, 150};
    const int   Nsz[4] = {150, 150, 150, 100};
    const float* w = Ws[l];
    const int K = Ksz[l], N = Nsz[l];

    int idx = blockIdx.x * 256 + threadIdx.x;   // 0..25599
    if (idx < 25600) {
        int n = idx / 160, k = idx % 160;
        float v = (k < K && n < N) ? w[k * N + n] : 0.f;
        unsigned short h = f2bf(v);
        unsigned short lo = f2bf(v - bf2f(h));
        Wt[(size_t)l * 51200 + idx]         = h;
        Wt[(size_t)l * 51200 + 25600 + idx] = lo;
    }
    if (blockIdx.x == 0 && threadIdx.x < 160)
        bfp[l * 160 + threadIdx.x] = (threadIdx.x < (unsigned)N) ? Bs[l][threadIdx.x] : 0.f;
}

// ---------------- Kernel 1: marshalling (round-0 proven version, ~150us) ----
// At the read-request-rate floor (10M lines / ~67 G-lines/s). Six
// restructurings (R7-R11) and the RRb spill (R13) all failed to beat it.
__global__ __launch_bounds__(256) void k_marshal(
    const float* __restrict__ obj, const float* __restrict__ S,
    const float* __restrict__ RRm, const float* __restrict__ rinfo,
    float* __restrict__ bmp)
{
    __shared__ float sobj[500 * NF_];
    const int b = blockIdx.y, z = blockIdx.z;
    const int n0 = z * 500;
    for (int i = threadIdx.x; i < 500 * NF_; i += 256)
        sobj[i] = obj[(size_t)b * O_ * NF_ + (size_t)n0 * NF_ + i];
    __syncthreads();

    const int r = blockIdx.x * 256 + threadIdx.x;
    if (r >= R_) return;

    const size_t base = (size_t)b * O_ * R_ + (size_t)n0 * R_ + r;
    const float* Sp = S + base;
    const float* Rp = RRm + base;

    float ss[NF_] = {0.f, 0.f, 0.f, 0.f, 0.f, 0.f};
    float rs[NF_] = {0.f, 0.f, 0.f, 0.f, 0.f, 0.f};

    #pragma unroll 4
    for (int n = 0; n < 500; ++n) {
        float sv = Sp[(size_t)n * R_];
        float rv = Rp[(size_t)n * R_];
        #pragma unroll
        for (int f = 0; f < NF_; ++f) {
            float o = sobj[n * NF_ + f];
            ss[f] = fmaf(sv, o, ss[f]);
            rs[f] = fmaf(rv, o, rs[f]);
        }
    }

    float* outp = bmp + ((size_t)z * 80000 + (size_t)b * R_ + r) * 16;
    #pragma unroll
    for (int f = 0; f < NF_; ++f) {
        outp[f]     = ss[f];
        outp[6 + f] = rs[f];
    }
    outp[12] = (z == 0) ? rinfo[(size_t)b * R_ + r] : 0.f;
}

// ---------------- Kernel 2: relational MLP, 128-row / 2M x 4N ---------------
// 625 blocks x 512 threads (8 waves = 2 wm x 4 wn). Wave owns 64 rows
// (4 m-frags) x {3,3,2,2} n-tiles. Per weight fragment: 2 loads -> 8 MFMAs
// (4:1; R12 was 2:1) and block count halves => weight L2 traffic ~1GB->500MB.
// acc[4][3] = 48 VGPR (R5's 80-VGPR blow-up avoided). Numerics identical to
// R12 (same fragments, same per-output accumulation order).
template<int NT>
__device__ __forceinline__ void layer_mm4(
    const unsigned short (*act)[168],
    const unsigned short* __restrict__ Wh, const unsigned short* __restrict__ Wl,
    int arow0, int koff, int cl, int nb, f32x4 (*acc)[3])
{
    #pragma unroll
    for (int m = 0; m < 4; ++m)
        #pragma unroll
        for (int j = 0; j < NT; ++j) acc[m][j] = (f32x4){0.f, 0.f, 0.f, 0.f};
    #pragma unroll
    for (int ks = 0; ks < 5; ++ks) {
        bf16x8 a0 = *(const bf16x8*)&act[arow0 +  0][ks * 32 + koff];
        bf16x8 a1 = *(const bf16x8*)&act[arow0 + 16][ks * 32 + koff];
        bf16x8 a2 = *(const bf16x8*)&act[arow0 + 32][ks * 32 + koff];
        bf16x8 a3 = *(const bf16x8*)&act[arow0 + 48][ks * 32 + koff];
        #pragma unroll
        for (int j = 0; j < NT; ++j) {
            const size_t wo = (size_t)((nb + j) * 16 + cl) * 160 + ks * 32 + koff;
            bf16x8 wh = *(const bf16x8*)(Wh + wo);
            bf16x8 wl = *(const bf16x8*)(Wl + wo);
            acc[0][j] = MFMA16(a0, wh, acc[0][j], 0, 0, 0);
            acc[0][j] = MFMA16(a0, wl, acc[0][j], 0, 0, 0);
            acc[1][j] = MFMA16(a1, wh, acc[1][j], 0, 0, 0);
            acc[1][j] = MFMA16(a1, wl, acc[1][j], 0, 0, 0);
            acc[2][j] = MFMA16(a2, wh, acc[2][j], 0, 0, 0);
            acc[2][j] = MFMA16(a2, wl, acc[2][j], 0, 0, 0);
            acc[3][j] = MFMA16(a3, wh, acc[3][j], 0, 0, 0);
            acc[3][j] = MFMA16(a3, wl, acc[3][j], 0, 0, 0);
        }
    }
}

template<int NT>
__device__ __forceinline__ void l1_mm4(
    const unsigned short (*act)[168], const unsigned short (*alo)[32],
    const unsigned short* __restrict__ Wt,
    int arow0, int koff, int cl, int nb, f32x4 (*acc)[3])
{
    const unsigned short* Wh = Wt;
    const unsigned short* Wl = Wt + 25600;
    bf16x8 ah0 = *(const bf16x8*)&act[arow0 +  0][koff];
    bf16x8 ah1 = *(const bf16x8*)&act[arow0 + 16][koff];
    bf16x8 ah2 = *(const bf16x8*)&act[arow0 + 32][koff];
    bf16x8 ah3 = *(const bf16x8*)&act[arow0 + 48][koff];
    bf16x8 al0 = *(const bf16x8*)&alo[arow0 +  0][koff];
    bf16x8 al1 = *(const bf16x8*)&alo[arow0 + 16][koff];
    bf16x8 al2 = *(const bf16x8*)&alo[arow0 + 32][koff];
    bf16x8 al3 = *(const bf16x8*)&alo[arow0 + 48][koff];
    #pragma unroll
    for (int j = 0; j < NT; ++j) {
        const size_t wo = (size_t)((nb + j) * 16 + cl) * 160 + koff;
        bf16x8 wh = *(const bf16x8*)(Wh + wo);
        bf16x8 wl = *(const bf16x8*)(Wl + wo);
        f32x4 a;
        a = (f32x4){0.f, 0.f, 0.f, 0.f};
        a = MFMA16(ah0, wh, a, 0, 0, 0); a = MFMA16(ah0, wl, a, 0, 0, 0);
        a = MFMA16(al0, wh, a, 0, 0, 0); acc[0][j] = a;
        a = (f32x4){0.f, 0.f, 0.f, 0.f};
        a = MFMA16(ah1, wh, a, 0, 0, 0); a = MFMA16(ah1, wl, a, 0, 0, 0);
        a = MFMA16(al1, wh, a, 0, 0, 0); acc[1][j] = a;
        a = (f32x4){0.f, 0.f, 0.f, 0.f};
        a = MFMA16(ah2, wh, a, 0, 0, 0); a = MFMA16(ah2, wl, a, 0, 0, 0);
        a = MFMA16(al2, wh, a, 0, 0, 0); acc[2][j] = a;
        a = (f32x4){0.f, 0.f, 0.f, 0.f};
        a = MFMA16(ah3, wh, a, 0, 0, 0); a = MFMA16(ah3, wl, a, 0, 0, 0);
        a = MFMA16(al3, wh, a, 0, 0, 0); acc[3][j] = a;
    }
}

template<int NT>
__device__ __forceinline__ void epi4(
    f32x4 (*acc)[3], const float* __restrict__ bias,
    unsigned short (*out)[168], int m0, int cl, int rg0, int nb)
{
    #pragma unroll
    for (int m = 0; m < 4; ++m) {
        #pragma unroll
        for (int j = 0; j < NT; ++j) {
            int col = (nb + j) * 16 + cl;
            float bv = bias[col];
            #pragma unroll
            for (int rg = 0; rg < 4; ++rg) {
                float v = fmaxf(acc[m][j][rg] + bv, 0.f);
                out[m0 + m * 16 + rg0 + rg][col] = f2bf(v);
            }
        }
    }
}

__global__ __launch_bounds__(512) void k_mlp(
    const float* __restrict__ bmp, unsigned short* __restrict__ Et,
    const unsigned short* __restrict__ Wt, const float* __restrict__ bfp)
{
    __shared__ unsigned short act[128][168];  // 43 KB, in-place layers
    __shared__ unsigned short alo[128][32];   // 8 KB, lo of layer-1 input
    const int t = threadIdx.x;
    const size_t row0 = (size_t)blockIdx.x * 128;   // 625 blocks exact

    for (int idx = t; idx < 128 * 32; idx += 512) {
        int rr = idx >> 5, k = idx & 31;
        float v = 0.f;
        if (k < 13)
            v = bmp[(row0 + rr) * 16 + k]
              + bmp[(size_t)80000 * 16 + (row0 + rr) * 16 + k];
        unsigned short h = f2bf(v);
        act[rr][k] = h;
        alo[rr][k] = f2bf(v - bf2f(h));
    }
    __syncthreads();

    const int lane = t & 63, wave = t >> 6;
    const int wm = wave >> 2, wn = wave & 3;
    const int m0    = wm * 64;
    const int arow0 = m0 + (lane & 15);
    const int koff  = (lane >> 4) * 8;
    const int cl    = lane & 15;
    const int rg0   = (lane >> 4) * 4;

    // n-tile split: layers 1-3 (10 tiles) -> {3,3,2,2} at nb {0,3,6,8};
    // layer 4 (7 tiles) -> {2,2,2,1} at nb {0,2,4,6}
    const int NB123[4] = {0, 3, 6, 8};
    const int NB4[4]   = {0, 2, 4, 6};
    const int nb123 = NB123[wn];
    const int nb4   = NB4[wn];

    f32x4 acc[4][3];

    // ---- layer 1
    if (wn < 2) l1_mm4<3>(act, alo, Wt, arow0, koff, cl, nb123, acc);
    else        l1_mm4<2>(act, alo, Wt, arow0, koff, cl, nb123, acc);
    __syncthreads();
    if (wn < 2) epi4<3>(acc, bfp + 0 * 160, act, m0, cl, rg0, nb123);
    else        epi4<2>(acc, bfp + 0 * 160, act, m0, cl, rg0, nb123);
    __syncthreads();

    // ---- layer 2
    if (wn < 2) layer_mm4<3>(act, Wt + 1 * 51200, Wt + 1 * 51200 + 25600, arow0, koff, cl, nb123, acc);
    else        layer_mm4<2>(act, Wt + 1 * 51200, Wt + 1 * 51200 + 25600, arow0, koff, cl, nb123, acc);
    __syncthreads();
    if (wn < 2) epi4<3>(acc, bfp + 1 * 160, act, m0, cl, rg0, nb123);
    else        epi4<2>(acc, bfp + 1 * 160, act, m0, cl, rg0, nb123);
    __syncthreads();

    // ---- layer 3
    if (wn < 2) layer_mm4<3>(act, Wt + 2 * 51200, Wt + 2 * 51200 + 25600, arow0, koff, cl, nb123, acc);
    else        layer_mm4<2>(act, Wt + 2 * 51200, Wt + 2 * 51200 + 25600, arow0, koff, cl, nb123, acc);
    __syncthreads();
    if (wn < 2) epi4<3>(acc, bfp + 2 * 160, act, m0, cl, rg0, nb123);
    else        epi4<2>(acc, bfp + 2 * 160, act, m0, cl, rg0, nb123);
    __syncthreads();

    // ---- layer 4 (7 tiles)
    if (wn < 3) layer_mm4<2>(act, Wt + 3 * 51200, Wt + 3 * 51200 + 25600, arow0, koff, cl, nb4, acc);
    else        layer_mm4<1>(act, Wt + 3 * 51200, Wt + 3 * 51200 + 25600, arow0, koff, cl, nb4, acc);
    __syncthreads();
    if (wn < 3) epi4<2>(acc, bfp + 3 * 160, act, m0, cl, rg0, nb4);
    else        epi4<1>(acc, bfp + 3 * 160, act, m0, cl, rg0, nb4);
    __syncthreads();

    // write E transposed bf16: Et[b][j][r], rows j=100..127 zeroed
    for (int idx = t; idx < 128 * 128; idx += 512) {
        int rr = idx & 127, j = idx >> 7;
        size_t gr = row0 + rr;
        int b = (int)(gr / R_);
        int r = (int)(gr - (size_t)b * R_);
        Et[((size_t)(b * EDP_ + j)) * R_ + r] = (j < 100) ? act[rr][j] : (unsigned short)0;
    }
}

// ---------------- Kernel 3: aggregation, M=128 per block (R12 proven) -------
__global__ __launch_bounds__(256) void k_agg(
    const float* __restrict__ RRm, const unsigned short* __restrict__ Et,
    float* __restrict__ part)
{
    __shared__ unsigned short sB[2][128][36];   // pad 36: 18-dword row stride
    const int t = threadIdx.x;
    const int mt = blockIdx.x, b = blockIdx.y, kz = blockIdx.z;
    const int lane = t & 63, wave = t >> 6;
    const int k0 = kz * CHUNK_;

    // B-stage: 128 rows x 32 bf16 per k-step = 512 x 16B chunks; 2 per thread
    const int br0 = t >> 2, bc0 = (t & 3) * 8;       // rows 0..63
    const int br1 = br0 + 64;                        // rows 64..127
    const unsigned short* EtB = Et + (size_t)b * EDP_ * R_;

    // A: two per-lane rows (m-groups), clamped (rows >=1000 dup 999; their
    // part rows are padding, never read by k_obj)
    const int cl = lane & 15, koff = (lane >> 4) * 8;
    int n0 = mt * 128 + wave * 32 + cl;
    int n1 = n0 + 16;
    if (n0 > 999) n0 = 999;
    if (n1 > 999) n1 = 999;
    const float* Ap0 = RRm + ((size_t)(b * O_) + n0) * R_ + k0 + koff;
    const float* Ap1 = RRm + ((size_t)(b * O_) + n1) * R_ + k0 + koff;

    f32x4 acc[2][8] = {};
    float4 a0c, a1c, a2c, a3c;
    float4 a0n = {0,0,0,0}, a1n = {0,0,0,0}, a2n = {0,0,0,0}, a3n = {0,0,0,0};

    // prologue: stage B + load A for iter 0
    {
        ushort8v v0 = *(const ushort8v*)(EtB + (size_t)br0 * R_ + k0 + bc0);
        ushort8v v1 = *(const ushort8v*)(EtB + (size_t)br1 * R_ + k0 + bc0);
        *(ushort8v*)&sB[0][br0][bc0] = v0;
        *(ushort8v*)&sB[0][br1][bc0] = v1;
        a0c = *(const float4*)(Ap0 + 0);
        a1c = *(const float4*)(Ap0 + 4);
        a2c = *(const float4*)(Ap1 + 0);
        a3c = *(const float4*)(Ap1 + 4);
    }
    __syncthreads();

    for (int it = 0; it < CHUNK_ / 32; ++it) {
        const int cur = it & 1, nxt = cur ^ 1;
        const bool more = (it + 1 < CHUNK_ / 32);
        ushort8v v0, v1;
        if (more) {
            // issue next-iter loads EARLY (hide HBM latency under MFMA phase)
            const int kb = k0 + (it + 1) * 32;
            v0 = *(const ushort8v*)(EtB + (size_t)br0 * R_ + kb + bc0);
            v1 = *(const ushort8v*)(EtB + (size_t)br1 * R_ + kb + bc0);
            a0n = *(const float4*)(Ap0 + (it + 1) * 32);
            a1n = *(const float4*)(Ap0 + (it + 1) * 32 + 4);
            a2n = *(const float4*)(Ap1 + (it + 1) * 32);
            a3n = *(const float4*)(Ap1 + (it + 1) * 32 + 4);
        }
        // convert A (cur) to bf16 fragments
        bf16x8 af0, af1;
        af0[0] = (short)f2bf(a0c.x); af0[1] = (short)f2bf(a0c.y);
        af0[2] = (short)f2bf(a0c.z); af0[3] = (short)f2bf(a0c.w);
        af0[4] = (short)f2bf(a1c.x); af0[5] = (short)f2bf(a1c.y);
        af0[6] = (short)f2bf(a1c.z); af0[7] = (short)f2bf(a1c.w);
        af1[0] = (short)f2bf(a2c.x); af1[1] = (short)f2bf(a2c.y);
        af1[2] = (short)f2bf(a2c.z); af1[3] = (short)f2bf(a2c.w);
        af1[4] = (short)f2bf(a3c.x); af1[5] = (short)f2bf(a3c.y);
        af1[6] = (short)f2bf(a3c.z); af1[7] = (short)f2bf(a3c.w);
        #pragma unroll
        for (int ni = 0; ni < 8; ++ni) {
            bf16x8 bf = *(const bf16x8*)&sB[cur][ni * 16 + cl][koff];
            acc[0][ni] = MFMA16(af0, bf, acc[0][ni], 0, 0, 0);
            acc[1][ni] = MFMA16(af1, bf, acc[1][ni], 0, 0, 0);
        }
        if (more) {
            *(ushort8v*)&sB[nxt][br0][bc0] = v0;
            *(ushort8v*)&sB[nxt][br1][bc0] = v1;
        }
        __syncthreads();
        a0c = a0n; a1c = a1n; a2c = a2n; a3c = a3n;
    }

    // store partials: C/D layout col=lane&15, row=(lane>>4)*4+rg
    float* pp = part + ((size_t)(kz * 4 + b) * MPAD_) * 128;
    #pragma unroll
    for (int mg = 0; mg < 2; ++mg) {
        const int rowb = mt * 128 + wave * 32 + mg * 16 + (lane >> 4) * 4;
        #pragma unroll
        for (int ni = 0; ni < 8; ++ni)
            #pragma unroll
            for (int rg = 0; rg < 4; ++rg)
                pp[(size_t)(rowb + rg) * 128 + ni * 16 + cl] = acc[mg][ni][rg];
    }
}

// ---------------- Kernel 4: object MLP (sums agg partials) ------------------
__global__ __launch_bounds__(256) void k_obj(
    const float* __restrict__ obj, const float* __restrict__ part,
    const float* __restrict__ ow1, const float* __restrict__ ob1,
    const float* __restrict__ ow2, const float* __restrict__ ob2,
    float* __restrict__ out)
{
    __shared__ float C[8][112];
    __shared__ float h[8][104];
    const int t = threadIdx.x;
    const int g0 = blockIdx.x * 8;

    for (int idx = t; idx < 8 * NF_; idx += 256) {
        int rr = idx / NF_, f = idx % NF_;
        C[rr][f] = obj[(size_t)(g0 + rr) * NF_ + f];
    }
    for (int idx = t; idx < 8 * 100; idx += 256) {
        int rr = idx / 100, f = idx % 100;
        int g = g0 + rr, b = g / 1000, n = g % 1000;
        float s = 0.f;
        for (int z = 0; z < KS_; ++z)
            s += part[((size_t)(z * 4 + b) * MPAD_ + n) * 128 + f];
        C[rr][6 + f] = s;
    }
    __syncthreads();

    for (int idx = t; idx < 8 * 100; idx += 256) {
        int rr = idx / 100, j = idx % 100;
        float acc = ob1[j];
        for (int k = 0; k < 106; ++k)
            acc = fmaf(C[rr][k], ow1[k * 100 + j], acc);
        h[rr][j] = fmaxf(acc, 0.f);
    }
    __syncthreads();

    if (t < 16) {
        int rr = t >> 1, j = t & 1;
        float acc = ob2[j];
        for (int k = 0; k < 100; ++k)
            acc = fmaf(h[rr][k], ow2[k * 2 + j], acc);
        out[(size_t)(g0 + rr) * 2 + j] = acc;
    }
}

// ---------------- launch ----------------------------------------------------
extern "C" void kernel_launch(void* const* d_in, const int* in_sizes, int n_in,
                              void* d_out, int out_size, void* d_ws, size_t ws_size,
                              hipStream_t stream)
{
    const float* obj   = (const float*)d_in[0];
    const float* S     = (const float*)d_in[1];
    const float* RRm   = (const float*)d_in[2];
    const float* rinfo = (const float*)d_in[3];
    const float* rw1   = (const float*)d_in[4];
    const float* rb1   = (const float*)d_in[5];
    const float* rw2   = (const float*)d_in[6];
    const float* rb2   = (const float*)d_in[7];
    const float* rw3   = (const float*)d_in[8];
    const float* rb3   = (const float*)d_in[9];
    const float* rw4   = (const float*)d_in[10];
    const float* rb4   = (const float*)d_in[11];
    const float* ow1   = (const float*)d_in[12];
    const float* ob1   = (const float*)d_in[13];
    const float* ow2   = (const float*)d_in[14];
    const float* ob2   = (const float*)d_in[15];

    float* ws            = (float*)d_ws;
    float* bmp           = ws;
    unsigned short* Et   = (unsigned short*)(ws + ET_OFF);
    float* part          = ws + PART_OFF;
    unsigned short* Wt   = (unsigned short*)(ws + PART_OFF);  // aliases part head
    float* bfp           = ws + PART_OFF + (WT_USHORTS / 2);
    float* out           = (float*)d_out;

    k_prep<<<dim3(100, 4), 256, 0, stream>>>(rw1, rb1, rw2, rb2, rw3, rb3, rw4, rb4,
                                             Wt, bfp);
    k_marshal<<<dim3(79, 4, 2), 256, 0, stream>>>(obj, S, RRm, rinfo, bmp);
    k_mlp<<<dim3(625), 512, 0, stream>>>(bmp, Et, Wt, bfp);
    k_agg<<<dim3(8, 4, KS_), 256, 0, stream>>>(RRm, Et, part);
    k_obj<<<dim3(500), 256, 0, stream>>>(obj, part, ow1, ob1, ow2, ob2, out);
}